// Round 14
// baseline (140.244 us; speedup 1.0000x reference)
//
#include <hip/hip_runtime.h>
#include <math.h>

// ProxyNCA loss, MFMA version — round 14.
// logit_ic = 18 * xhat_i . phat_c ;  nll_i = log(sum_c exp(logit_ic)) - logit_{i,T_i}
// Both operands prescaled by sqrt(18*log2(e)) = 5.0959308 into bf16; the
// 16x16x32 bf16 MFMA accumulator holds log2(e)*logit, so exp = v_exp_f32.
//
// Round 14 vs round 13: ONE variable — __launch_bounds__(512,8).
// Session occupancy ledger: (512,8)->79% (R4), (512,4)->37% (R5),
// (512,2)->20-29% (R9/R13) — occupancy tracks the waves-per-EU hint, not
// VGPR count. (512,2) has been capping residency at ~2 waves/SIMD all
// session. R13's kernel measured 52 VGPR — it genuinely fits the 64-reg
// budget that 8 waves/EU demands (unlike R4, which needed ~100 -> spill).
// Everything else identical to R13: P tile in LDS (staged once via
// global_load_lds, conflict-free 16B lane reads), CBLK=128, RSPLIT=2,
// 2-tile ILP, single-shfl epilogue, 256-block rowred.

#define NROWS 4096
#define NCLS  65536
#define DIM   64
#define CBLK  128                 // classes per block
#define NBLK  (NCLS / CBLK)       // 512 class-blocks
#define RSPLIT 2                  // row halves -> grid 1024
#define NCH   (CBLK / 16)         // 8 MFMA chunks of 16 classes
#define NPB   (NCLS / 4)          // prep blocks for P (4 rows each)

typedef __attribute__((ext_vector_type(8))) short short8;
typedef __attribute__((ext_vector_type(4))) float f32x4;

#define PRESCALE 5.0959308f       // sqrt(18 * log2(e))

__device__ __forceinline__ short bf16rne(float f) {
    union { float f; unsigned u; } v; v.f = f;
    unsigned r = (v.u + 0x7fffu + ((v.u >> 16) & 1u)) >> 16;
    return (short)r;
}

// ---- fused prep: blocks [0,NPB) pack P -> Pb; blocks [NPB,..) do X/st ----
// Pb ushort index for (class row, dim d):
//   chunk=row>>4, half=d>>5, lane=(row&15)+16*((d>>3)&3), elem=d&7
//   idx = chunk*1024 + half*512 + lane*8 + elem
// Class-block b = chunks 8b..8b+7 = 16KB contiguous at byte offset b*16384.
__global__ void k_prep(const float* __restrict__ X, const float* __restrict__ P,
                       const int* __restrict__ T,
                       unsigned short* __restrict__ Pb,
                       unsigned short* __restrict__ Xb, float* __restrict__ st,
                       float* __restrict__ out) {
    int bx = blockIdx.x;
    int t  = threadIdx.x;
    if (bx < NPB) {
        int row = bx * 4 + (t >> 6);
        int d   = t & 63;
        float v  = P[row * DIM + d];
        float sq = v * v;
        #pragma unroll
        for (int off = 32; off > 0; off >>= 1) sq += __shfl_xor(sq, off);
        float sc = PRESCALE * rsqrtf(fmaxf(sq, 1e-24f));
        int idx = (row >> 4) * 1024 + (d >> 5) * 512
                + ((row & 15) + ((d >> 3) & 3) * 16) * 8 + (d & 7);
        Pb[idx] = (unsigned short)bf16rne(v * sc);
    } else {
        if (bx == NPB && t == 0) out[0] = 0.0f;
        int row  = (bx - NPB) * 4 + (t >> 6);
        int lane = t & 63;
        int tc   = T[row];
        float xv = X[row * DIM + lane];
        float pv = P[tc  * DIM + lane];
        float x2 = xv * xv, p2 = pv * pv, xp = xv * pv;
        #pragma unroll
        for (int off = 32; off > 0; off >>= 1) {
            x2 += __shfl_xor(x2, off);
            p2 += __shfl_xor(p2, off);
            xp += __shfl_xor(xp, off);
        }
        float rx = rsqrtf(fmaxf(x2, 1e-24f));
        Xb[row * DIM + lane] = (unsigned short)bf16rne(xv * (PRESCALE * rx));
        if (lane == 0)
            st[row] = 18.0f * xp * rx * rsqrtf(fmaxf(p2, 1e-24f));
    }
}

// ---- main: block (b,h): classes [b*128,+128) x rows [h*2048,+2048) -------
// P tile (16KB) staged once into LDS; frags re-read per chunk (ds_read_b128,
// lane-contiguous -> conflict-free). 8 waves; wave w, iter it handles
// row-tiles at rows h*2048 + 256*it + w*16 (+128 for B tile).
// mfma(P_frag, X_frag): C col = lane&15 = x-row, regs = 4 classes.
__global__ __launch_bounds__(512, 8)
void k_main(const unsigned short* __restrict__ Pbu, const unsigned short* __restrict__ Xb,
            float* __restrict__ psum) {
    __shared__ __align__(16) unsigned short plds[NCH * 2 * 512];   // 16 KB

    int t = threadIdx.x;
    int w = t >> 6;
    int l = t & 63;
    int bx = blockIdx.x;
    int b  = bx & (NBLK - 1);
    int h  = bx >> 9;
    int lm = l & 15;              // x-row within tile
    int lk = l >> 4;              // k-group

    // ---- stage P tile: 16KB linear copy (identity layout), 2 calls/wave
    {
        const char* src = reinterpret_cast<const char*>(Pbu)
                        + (size_t)b * 16384 + w * 1024 + l * 16;
        __builtin_amdgcn_global_load_lds(
            (const __attribute__((address_space(1))) unsigned int*)src,
            (__attribute__((address_space(3))) unsigned int*)((char*)plds + w * 1024),
            16, 0, 0);
        __builtin_amdgcn_global_load_lds(
            (const __attribute__((address_space(1))) unsigned int*)(src + 8192),
            (__attribute__((address_space(3))) unsigned int*)((char*)plds + 8192 + w * 1024),
            16, 0, 0);
    }
    __syncthreads();              // compiler drains vmcnt before barrier

    const f32x4 zero = {0.0f, 0.0f, 0.0f, 0.0f};

    // ---- row sweep: 8 iterations x 2 independent tiles (A and A+128 rows)
    const short8* xpA = reinterpret_cast<const short8*>(
        Xb + (h * 2048 + w * 16 + lm) * DIM + lk * 8);
    // psum layout: [block][row][2] f32; lanes l<32 store part lk.
    float* prow = psum + ((size_t)b * NROWS + h * 2048 + w * 16 + lm) * 2 + lk;
    const char* pl = (const char*)plds + l * 16;

    #pragma unroll 1
    for (int it = 0; it < 8; ++it) {
        short8 xA0 = xpA[0];
        short8 xA1 = xpA[4];          // +32 shorts (k 32..63)
        short8 xB0 = xpA[1024];       // +8192 shorts = +128 rows
        short8 xB1 = xpA[1028];

        float eA0 = 0.f, eA1 = 0.f, eA2 = 0.f, eA3 = 0.f;
        float eB0 = 0.f, eB1 = 0.f, eB2 = 0.f, eB3 = 0.f;
        #pragma unroll
        for (int ch = 0; ch < NCH; ++ch) {
            short8 p0 = *reinterpret_cast<const short8*>(pl + ch * 2048);
            short8 p1 = *reinterpret_cast<const short8*>(pl + ch * 2048 + 1024);
            f32x4 cA = __builtin_amdgcn_mfma_f32_16x16x32_bf16(p0, xA0, zero, 0, 0, 0);
            cA = __builtin_amdgcn_mfma_f32_16x16x32_bf16(p1, xA1, cA, 0, 0, 0);
            f32x4 cB = __builtin_amdgcn_mfma_f32_16x16x32_bf16(p0, xB0, zero, 0, 0, 0);
            cB = __builtin_amdgcn_mfma_f32_16x16x32_bf16(p1, xB1, cB, 0, 0, 0);
            eA0 += __builtin_amdgcn_exp2f(cA[0]);
            eA1 += __builtin_amdgcn_exp2f(cA[1]);
            eA2 += __builtin_amdgcn_exp2f(cA[2]);
            eA3 += __builtin_amdgcn_exp2f(cA[3]);
            eB0 += __builtin_amdgcn_exp2f(cB[0]);
            eB1 += __builtin_amdgcn_exp2f(cB[1]);
            eB2 += __builtin_amdgcn_exp2f(cB[2]);
            eB3 += __builtin_amdgcn_exp2f(cB[3]);
        }
        float sA = (eA0 + eA1) + (eA2 + eA3);
        float sB = (eB0 + eB1) + (eB2 + eB3);
        sA += __shfl_xor(sA, 32);     // lane holds partial over {lk, lk^2}
        sB += __shfl_xor(sB, 32);
        if (l < 32) {
            prow[0]       = sA;       // rows h*2048 + 256*it + w*16 .. +15
            prow[128 * 2] = sB;       // +128 rows
        }

        xpA += 2048;                  // +256 rows
        prow += 256 * 2;
    }
}

// ---- per-row finish + global mean, 256 blocks x 16 rows ------------------
// thread t: j = t>>4 sums i-range [j*32, +32); ri = t&15 = row in block.
__global__ void k_rowred(const float* __restrict__ psum, const float* __restrict__ st,
                         float* __restrict__ out) {
    __shared__ float red[256];
    __shared__ float rnll[16];
    int t  = threadIdx.x;
    int j  = t >> 4;
    int ri = t & 15;
    int r  = blockIdx.x * 16 + ri;
    const float2* p2 = reinterpret_cast<const float2*>(psum) + r;
    float s = 0.0f;
    #pragma unroll 4
    for (int i = j * 32; i < j * 32 + 32; ++i) {
        float2 v = p2[(size_t)i * NROWS];
        s += v.x + v.y;
    }
    red[t] = s;
    __syncthreads();
    if (t < 128) red[t] += red[t + 128];
    __syncthreads();
    if (t < 64)  red[t] += red[t + 64];
    __syncthreads();
    if (t < 32)  red[t] += red[t + 32];
    __syncthreads();
    if (t < 16) {
        float tot = red[t] + red[t + 16];
        rnll[t] = logf(tot) - st[r];
    }
    __syncthreads();
    if (t == 0) {
        float a = 0.0f;
        #pragma unroll
        for (int k = 0; k < 16; ++k) a += rnll[k];
        atomicAdd(out, a * (1.0f / (float)NROWS));
    }
}

extern "C" void kernel_launch(void* const* d_in, const int* in_sizes, int n_in,
                              void* d_out, int out_size, void* d_ws, size_t ws_size,
                              hipStream_t stream) {
    const float* X = (const float*)d_in[0];
    const float* P = (const float*)d_in[1];
    const int*   T = (const int*)  d_in[3];   // d_in[2] = indices (unused)
    float* out = (float*)d_out;

    char* ws = (char*)d_ws;
    unsigned short* Xb = (unsigned short*)ws;                 // 512 KB
    float* st   = (float*)(ws + (512 << 10));                 // 16 KB
    unsigned short* Pb = (unsigned short*)(ws + (576 << 10)); // 8 MB (packed frags)
    float* psum = (float*)(ws + (9 << 20));                   // 16 MB (512 x 4096 x 2)

    k_prep  <<<NPB + NROWS / 4, 256, 0, stream>>>(X, P, T, Pb, Xb, st, out);
    k_main  <<<NBLK * RSPLIT, 512, 0, stream>>>(Pb, Xb, psum);
    k_rowred<<<256, 256, 0, stream>>>(psum, st, out);
}

// Round 15
// 65.479 us; speedup vs baseline: 2.1418x; 2.1418x over previous
//
#include <hip/hip_runtime.h>
#include <math.h>

// ProxyNCA loss, MFMA version — round 15.
// logit_ic = 18 * xhat_i . phat_c ;  nll_i = log(sum_c exp(logit_ic)) - logit_{i,T_i}
// Both operands prescaled by sqrt(18*log2(e)) = 5.0959308 into bf16; the
// 16x16x32 bf16 MFMA accumulator holds log2(e)*logit, so exp = v_exp_f32.
//
// Round 15 vs rounds 13/14: ONE variable — __launch_bounds__(512,4).
// Session ledger: R5 and R13 both report VGPR=52 but occupancy 37% vs 29%
// -> reported VGPR_Count is not the residency limiter; the AGPR side of the
// unified file is sized by the waves-per-EU budget. (512,2) -> lavish acc
// allocation, ~2.3 waves/SIMD. (512,8) -> 64-reg cap, spill (R4/R14,
// FETCH 306MB). (512,4) = 128 budget is the untested middle for THIS kernel
// (R8 failed at (512,4) only because pb then lived in 64 arch regs; R13's
// P-in-LDS kernel needs ~52 arch + modest acc -> fits).
// Everything else identical to R13: P tile in LDS via global_load_lds,
// CBLK=128, RSPLIT=2, 2-tile ILP, single-shfl epilogue, 256-block rowred.

#define NROWS 4096
#define NCLS  65536
#define DIM   64
#define CBLK  128                 // classes per block
#define NBLK  (NCLS / CBLK)       // 512 class-blocks
#define RSPLIT 2                  // row halves -> grid 1024 (= 4 blocks/CU)
#define NCH   (CBLK / 16)         // 8 MFMA chunks of 16 classes
#define NPB   (NCLS / 4)          // prep blocks for P (4 rows each)

typedef __attribute__((ext_vector_type(8))) short short8;
typedef __attribute__((ext_vector_type(4))) float f32x4;

#define PRESCALE 5.0959308f       // sqrt(18 * log2(e))

__device__ __forceinline__ short bf16rne(float f) {
    union { float f; unsigned u; } v; v.f = f;
    unsigned r = (v.u + 0x7fffu + ((v.u >> 16) & 1u)) >> 16;
    return (short)r;
}

// ---- fused prep: blocks [0,NPB) pack P -> Pb; blocks [NPB,..) do X/st ----
// Pb ushort index for (class row, dim d):
//   chunk=row>>4, half=d>>5, lane=(row&15)+16*((d>>3)&3), elem=d&7
//   idx = chunk*1024 + half*512 + lane*8 + elem
// Class-block b = chunks 8b..8b+7 = 16KB contiguous at byte offset b*16384.
__global__ void k_prep(const float* __restrict__ X, const float* __restrict__ P,
                       const int* __restrict__ T,
                       unsigned short* __restrict__ Pb,
                       unsigned short* __restrict__ Xb, float* __restrict__ st,
                       float* __restrict__ out) {
    int bx = blockIdx.x;
    int t  = threadIdx.x;
    if (bx < NPB) {
        int row = bx * 4 + (t >> 6);
        int d   = t & 63;
        float v  = P[row * DIM + d];
        float sq = v * v;
        #pragma unroll
        for (int off = 32; off > 0; off >>= 1) sq += __shfl_xor(sq, off);
        float sc = PRESCALE * rsqrtf(fmaxf(sq, 1e-24f));
        int idx = (row >> 4) * 1024 + (d >> 5) * 512
                + ((row & 15) + ((d >> 3) & 3) * 16) * 8 + (d & 7);
        Pb[idx] = (unsigned short)bf16rne(v * sc);
    } else {
        if (bx == NPB && t == 0) out[0] = 0.0f;
        int row  = (bx - NPB) * 4 + (t >> 6);
        int lane = t & 63;
        int tc   = T[row];
        float xv = X[row * DIM + lane];
        float pv = P[tc  * DIM + lane];
        float x2 = xv * xv, p2 = pv * pv, xp = xv * pv;
        #pragma unroll
        for (int off = 32; off > 0; off >>= 1) {
            x2 += __shfl_xor(x2, off);
            p2 += __shfl_xor(p2, off);
            xp += __shfl_xor(xp, off);
        }
        float rx = rsqrtf(fmaxf(x2, 1e-24f));
        Xb[row * DIM + lane] = (unsigned short)bf16rne(xv * (PRESCALE * rx));
        if (lane == 0)
            st[row] = 18.0f * xp * rx * rsqrtf(fmaxf(p2, 1e-24f));
    }
}

// ---- main: block (b,h): classes [b*128,+128) x rows [h*2048,+2048) -------
// P tile (16KB) staged once into LDS; frags re-read per chunk (ds_read_b128,
// lane-contiguous -> conflict-free). 8 waves; wave w, iter it handles
// row-tiles at rows h*2048 + 256*it + w*16 (+128 for B tile).
// mfma(P_frag, X_frag): C col = lane&15 = x-row, regs = 4 classes.
__global__ __launch_bounds__(512, 4)
void k_main(const unsigned short* __restrict__ Pbu, const unsigned short* __restrict__ Xb,
            float* __restrict__ psum) {
    __shared__ __align__(16) unsigned short plds[NCH * 2 * 512];   // 16 KB

    int t = threadIdx.x;
    int w = t >> 6;
    int l = t & 63;
    int bx = blockIdx.x;
    int b  = bx & (NBLK - 1);
    int h  = bx >> 9;
    int lm = l & 15;              // x-row within tile
    int lk = l >> 4;              // k-group

    // ---- stage P tile: 16KB linear copy (identity layout), 2 calls/wave
    {
        const char* src = reinterpret_cast<const char*>(Pbu)
                        + (size_t)b * 16384 + w * 1024 + l * 16;
        __builtin_amdgcn_global_load_lds(
            (const __attribute__((address_space(1))) unsigned int*)src,
            (__attribute__((address_space(3))) unsigned int*)((char*)plds + w * 1024),
            16, 0, 0);
        __builtin_amdgcn_global_load_lds(
            (const __attribute__((address_space(1))) unsigned int*)(src + 8192),
            (__attribute__((address_space(3))) unsigned int*)((char*)plds + 8192 + w * 1024),
            16, 0, 0);
    }
    __syncthreads();              // compiler drains vmcnt before barrier

    const f32x4 zero = {0.0f, 0.0f, 0.0f, 0.0f};

    // ---- row sweep: 8 iterations x 2 independent tiles (A and A+128 rows)
    const short8* xpA = reinterpret_cast<const short8*>(
        Xb + (h * 2048 + w * 16 + lm) * DIM + lk * 8);
    // psum layout: [block][row][2] f32; lanes l<32 store part lk.
    float* prow = psum + ((size_t)b * NROWS + h * 2048 + w * 16 + lm) * 2 + lk;
    const char* pl = (const char*)plds + l * 16;

    #pragma unroll 1
    for (int it = 0; it < 8; ++it) {
        short8 xA0 = xpA[0];
        short8 xA1 = xpA[4];          // +32 shorts (k 32..63)
        short8 xB0 = xpA[1024];       // +8192 shorts = +128 rows
        short8 xB1 = xpA[1028];

        float eA0 = 0.f, eA1 = 0.f, eA2 = 0.f, eA3 = 0.f;
        float eB0 = 0.f, eB1 = 0.f, eB2 = 0.f, eB3 = 0.f;
        #pragma unroll
        for (int ch = 0; ch < NCH; ++ch) {
            short8 p0 = *reinterpret_cast<const short8*>(pl + ch * 2048);
            short8 p1 = *reinterpret_cast<const short8*>(pl + ch * 2048 + 1024);
            f32x4 cA = __builtin_amdgcn_mfma_f32_16x16x32_bf16(p0, xA0, zero, 0, 0, 0);
            cA = __builtin_amdgcn_mfma_f32_16x16x32_bf16(p1, xA1, cA, 0, 0, 0);
            f32x4 cB = __builtin_amdgcn_mfma_f32_16x16x32_bf16(p0, xB0, zero, 0, 0, 0);
            cB = __builtin_amdgcn_mfma_f32_16x16x32_bf16(p1, xB1, cB, 0, 0, 0);
            eA0 += __builtin_amdgcn_exp2f(cA[0]);
            eA1 += __builtin_amdgcn_exp2f(cA[1]);
            eA2 += __builtin_amdgcn_exp2f(cA[2]);
            eA3 += __builtin_amdgcn_exp2f(cA[3]);
            eB0 += __builtin_amdgcn_exp2f(cB[0]);
            eB1 += __builtin_amdgcn_exp2f(cB[1]);
            eB2 += __builtin_amdgcn_exp2f(cB[2]);
            eB3 += __builtin_amdgcn_exp2f(cB[3]);
        }
        float sA = (eA0 + eA1) + (eA2 + eA3);
        float sB = (eB0 + eB1) + (eB2 + eB3);
        sA += __shfl_xor(sA, 32);     // lane holds partial over {lk, lk^2}
        sB += __shfl_xor(sB, 32);
        if (l < 32) {
            prow[0]       = sA;       // rows h*2048 + 256*it + w*16 .. +15
            prow[128 * 2] = sB;       // +128 rows
        }

        xpA += 2048;                  // +256 rows
        prow += 256 * 2;
    }
}

// ---- per-row finish + global mean, 256 blocks x 16 rows ------------------
// thread t: j = t>>4 sums i-range [j*32, +32); ri = t&15 = row in block.
__global__ void k_rowred(const float* __restrict__ psum, const float* __restrict__ st,
                         float* __restrict__ out) {
    __shared__ float red[256];
    __shared__ float rnll[16];
    int t  = threadIdx.x;
    int j  = t >> 4;
    int ri = t & 15;
    int r  = blockIdx.x * 16 + ri;
    const float2* p2 = reinterpret_cast<const float2*>(psum) + r;
    float s = 0.0f;
    #pragma unroll 4
    for (int i = j * 32; i < j * 32 + 32; ++i) {
        float2 v = p2[(size_t)i * NROWS];
        s += v.x + v.y;
    }
    red[t] = s;
    __syncthreads();
    if (t < 128) red[t] += red[t + 128];
    __syncthreads();
    if (t < 64)  red[t] += red[t + 64];
    __syncthreads();
    if (t < 32)  red[t] += red[t + 32];
    __syncthreads();
    if (t < 16) {
        float tot = red[t] + red[t + 16];
        rnll[t] = logf(tot) - st[r];
    }
    __syncthreads();
    if (t == 0) {
        float a = 0.0f;
        #pragma unroll
        for (int k = 0; k < 16; ++k) a += rnll[k];
        atomicAdd(out, a * (1.0f / (float)NROWS));
    }
}

extern "C" void kernel_launch(void* const* d_in, const int* in_sizes, int n_in,
                              void* d_out, int out_size, void* d_ws, size_t ws_size,
                              hipStream_t stream) {
    const float* X = (const float*)d_in[0];
    const float* P = (const float*)d_in[1];
    const int*   T = (const int*)  d_in[3];   // d_in[2] = indices (unused)
    float* out = (float*)d_out;

    char* ws = (char*)d_ws;
    unsigned short* Xb = (unsigned short*)ws;                 // 512 KB
    float* st   = (float*)(ws + (512 << 10));                 // 16 KB
    unsigned short* Pb = (unsigned short*)(ws + (576 << 10)); // 8 MB (packed frags)
    float* psum = (float*)(ws + (9 << 20));                   // 16 MB (512 x 4096 x 2)

    k_prep  <<<NPB + NROWS / 4, 256, 0, stream>>>(X, P, T, Pb, Xb, st, out);
    k_main  <<<NBLK * RSPLIT, 512, 0, stream>>>(Pb, Xb, psum);
    k_rowred<<<256, 256, 0, stream>>>(psum, st, out);
}